// Round 1
// baseline (130.108 us; speedup 1.0000x reference)
//
#include <hip/hip_runtime.h>

// TripletLoss, B=4096, D=128, fp32. Batch-hard mining.
// Gram-trick distances: d2 = sq[i] + sq[j] - 2*dot(i,j).
// Phase1: GEMM-style tiled dot-product, 128x256 tile/block, 8x8 micro-tile,
//         merge per-row hard_pos (atomicMax) / hard_neg (atomicMin) via
//         uint bit-trick (valid for non-negative floats).
// Validity via label histogram: pos exists <=> cnt>=2, neg exists <=> cnt<B.

#define B_N 4096
#define D_K 128
#define TI 128      // i-rows per block
#define TJ 128      // j-cols per subtile
#define JCHUNK 256  // j-range per block (2 subtiles)
#define DC 32       // dims per LDS chunk
#define TIP 132     // padded LDS leading dim (keeps 16B alignment: 132*4=528=33*16)
#define MARGIN_F 0.3f

// ws layout (32-bit words):
//  [0..2)      accum (float): sum_loss, num_valid
//  [16..272)   hist (uint, 256)
//  [512..4608) hpb (uint bits of hard_pos, init 0)
//  [4608..8704) hnb (uint bits of hard_neg, init +inf)
//  [8704..12800) sqn (float, 4096)  -- fully written, no init needed

__global__ __launch_bounds__(256) void tl_init(unsigned* __restrict__ W) {
    int idx = blockIdx.x * 256 + threadIdx.x;
    if (idx < 8704) W[idx] = (idx >= 4608) ? 0x7F800000u : 0u;
}

__global__ __launch_bounds__(256) void tl_prep(const float* __restrict__ E,
                                               const int* __restrict__ labels,
                                               unsigned* __restrict__ hist,
                                               float* __restrict__ sqn) {
    int i = blockIdx.x * 256 + threadIdx.x;  // grid 16 -> 4096 threads
    atomicAdd(&hist[labels[i]], 1u);
    const float4* row = (const float4*)(E + (size_t)i * D_K);
    float s = 0.0f;
#pragma unroll
    for (int k = 0; k < D_K / 4; ++k) {
        float4 v = row[k];
        s = fmaf(v.x, v.x, s); s = fmaf(v.y, v.y, s);
        s = fmaf(v.z, v.z, s); s = fmaf(v.w, v.w, s);
    }
    sqn[i] = s;
}

__global__ __launch_bounds__(256) void tl_phase1(const float* __restrict__ E,
                                                 const int* __restrict__ labels,
                                                 const float* __restrict__ sqn,
                                                 unsigned* __restrict__ hpb,
                                                 unsigned* __restrict__ hnb) {
    __shared__ __align__(16) float Al[DC][TIP];  // dim-major A tile chunk
    __shared__ __align__(16) float Bl[DC][TIP];  // dim-major B tile chunk
    const int tid = threadIdx.x;
    const int tx = tid & 15, ty = tid >> 4;
    const int i0 = blockIdx.x * TI;
    const int jbase = blockIdx.y * JCHUNK;
    const int ibase = i0 + ty * 8;

    float maxpos[8], minneg[8], sqi[8];
    int li[8];
#pragma unroll
    for (int r = 0; r < 8; ++r) {
        maxpos[r] = -1.0f;
        minneg[r] = 3.0e38f;
        sqi[r] = sqn[ibase + r];
        li[r] = labels[ibase + r];
    }

    for (int js = 0; js < JCHUNK / TJ; ++js) {
        const int j0 = jbase + js * TJ;
        float acc[8][8];
#pragma unroll
        for (int r = 0; r < 8; ++r)
#pragma unroll
            for (int c = 0; c < 8; ++c) acc[r][c] = 0.0f;

        for (int dc = 0; dc < D_K / DC; ++dc) {
            const int d0 = dc * DC;
            __syncthreads();  // protect prior-iter LDS reads before restage
#pragma unroll
            for (int p = 0; p < 4; ++p) {
                int row = p * 32 + (tid >> 3);
                int f = tid & 7;
                float4 va = *(const float4*)&E[(size_t)(i0 + row) * D_K + d0 + 4 * f];
                Al[4 * f + 0][row] = va.x; Al[4 * f + 1][row] = va.y;
                Al[4 * f + 2][row] = va.z; Al[4 * f + 3][row] = va.w;
                float4 vb = *(const float4*)&E[(size_t)(j0 + row) * D_K + d0 + 4 * f];
                Bl[4 * f + 0][row] = vb.x; Bl[4 * f + 1][row] = vb.y;
                Bl[4 * f + 2][row] = vb.z; Bl[4 * f + 3][row] = vb.w;
            }
            __syncthreads();
#pragma unroll
            for (int d = 0; d < DC; ++d) {
                float4 a0 = *(const float4*)&Al[d][ty * 8];
                float4 a1 = *(const float4*)&Al[d][ty * 8 + 4];
                float4 b0 = *(const float4*)&Bl[d][tx * 8];
                float4 b1 = *(const float4*)&Bl[d][tx * 8 + 4];
                float a[8] = {a0.x, a0.y, a0.z, a0.w, a1.x, a1.y, a1.z, a1.w};
                float b[8] = {b0.x, b0.y, b0.z, b0.w, b1.x, b1.y, b1.z, b1.w};
#pragma unroll
                for (int r = 0; r < 8; ++r)
#pragma unroll
                    for (int c = 0; c < 8; ++c)
                        acc[r][c] = fmaf(a[r], b[c], acc[r][c]);
            }
        }
        // epilogue for this 128-col subtile
#pragma unroll
        for (int c = 0; c < 8; ++c) {
            int j = j0 + tx * 8 + c;
            int lj = labels[j];
            float sj = sqn[j];
#pragma unroll
            for (int r = 0; r < 8; ++r) {
                float d2 = sqi[r] + sj - 2.0f * acc[r][c];
                float dist = sqrtf(fmaxf(d2, 0.0f));
                bool same = (li[r] == lj);
                if (same) {
                    if (ibase + r != j) maxpos[r] = fmaxf(maxpos[r], dist);
                } else {
                    minneg[r] = fminf(minneg[r], dist);
                }
            }
        }
    }
    // reduce across the 16 tx lanes (same wave: lane = ty%4 *16 + tx)
#pragma unroll
    for (int r = 0; r < 8; ++r) {
        float mp = maxpos[r], mn = minneg[r];
#pragma unroll
        for (int s = 1; s < 16; s <<= 1) {
            mp = fmaxf(mp, __shfl_xor(mp, s));
            mn = fminf(mn, __shfl_xor(mn, s));
        }
        if (tx == 0) {
            // bit-trick atomics: valid only for non-negative floats, so guard sentinels
            if (mp >= 0.0f) atomicMax(&hpb[ibase + r], __float_as_uint(mp));
            if (mn < 2.9e38f) atomicMin(&hnb[ibase + r], __float_as_uint(mn));
        }
    }
}

__global__ __launch_bounds__(256) void tl_phase2(const unsigned* __restrict__ hpb,
                                                 const unsigned* __restrict__ hnb,
                                                 const int* __restrict__ labels,
                                                 const unsigned* __restrict__ hist,
                                                 float* __restrict__ accum) {
    int i = blockIdx.x * 256 + threadIdx.x;  // grid 16
    float hp = __uint_as_float(hpb[i]);
    float hn = __uint_as_float(hnb[i]);
    unsigned cnt = hist[labels[i]];
    bool valid = (cnt >= 2u) && (cnt < (unsigned)B_N);
    float pr = valid ? fmaxf(hp - hn + MARGIN_F, 0.0f) : 0.0f;
    float vv = valid ? 1.0f : 0.0f;
#pragma unroll
    for (int s = 32; s >= 1; s >>= 1) {
        pr += __shfl_down(pr, s);
        vv += __shfl_down(vv, s);
    }
    __shared__ float sp[4], sv[4];
    int w = threadIdx.x >> 6;
    if ((threadIdx.x & 63) == 0) { sp[w] = pr; sv[w] = vv; }
    __syncthreads();
    if (threadIdx.x == 0) {
        float tp = 0.0f, tv = 0.0f;
#pragma unroll
        for (int q = 0; q < 4; ++q) { tp += sp[q]; tv += sv[q]; }
        atomicAdd(&accum[0], tp);
        atomicAdd(&accum[1], tv);
    }
}

__global__ void tl_final(const float* __restrict__ accum, float* __restrict__ out) {
    if (threadIdx.x == 0) out[0] = accum[0] / fmaxf(accum[1], 1.0f);
}

extern "C" void kernel_launch(void* const* d_in, const int* in_sizes, int n_in,
                              void* d_out, int out_size, void* d_ws, size_t ws_size,
                              hipStream_t stream) {
    const float* E = (const float*)d_in[0];
    const int* labels = (const int*)d_in[1];
    float* out = (float*)d_out;

    unsigned* W = (unsigned*)d_ws;          // needs ~51.2 KB of ws
    float* accum = (float*)W;               // [0..2)
    unsigned* hist = W + 16;                // [16..272)
    unsigned* hpb = W + 512;                // [512..4608)
    unsigned* hnb = W + 4608;               // [4608..8704)
    float* sqn = (float*)(W + 8704);        // [8704..12800)

    tl_init<<<34, 256, 0, stream>>>(W);
    tl_prep<<<16, 256, 0, stream>>>(E, labels, hist, sqn);
    tl_phase1<<<dim3(B_N / TI, B_N / JCHUNK), 256, 0, stream>>>(E, labels, sqn, hpb, hnb);
    tl_phase2<<<16, 256, 0, stream>>>(hpb, hnb, labels, hist, accum);
    tl_final<<<1, 64, 0, stream>>>(accum, out);
}

// Round 2
// 88.151 us; speedup vs baseline: 1.4760x; 1.4760x over previous
//
#include <hip/hip_runtime.h>
#include <hip/hip_bf16.h>

// TripletLoss B=4096 D=128 fp32. Batch-hard mining via bf16 hi/lo MFMA Gram.
// Ecat[4096][256] bf16 = [hi | lo] so Ecat*Ecat^T = (hi+lo)(hi+lo)^T ~= E E^T
// (error ~2^-17 relative). Mine on d^2 (monotone), sqrt in phase2.
// 3 launches: prep (convert + sqn + init hpb/hnb), phase1 (MFMA GEMM +
// epilogue mining + bit-trick atomics), phase2 (hist + finalize, 1 block).

typedef __attribute__((ext_vector_type(8))) short short8;
typedef __attribute__((ext_vector_type(4))) float f32x4;

#define MARGIN_F 0.3f
#define WST 72  // LDS row stride in bf16: 144 B = 36 words -> even bank spread

__device__ inline unsigned short f2bf(float x) {
    __hip_bfloat16 h = __float2bfloat16(x);
    return *(unsigned short*)&h;
}
__device__ inline float bf2f(unsigned short u) {
    __hip_bfloat16 h;
    *(unsigned short*)&h = u;
    return __bfloat162float(h);
}

// grid 512 x 256: 32 threads per row (4096 rows)
__global__ __launch_bounds__(256) void tl_prep(const float* __restrict__ E,
                                               unsigned short* __restrict__ Ecat,
                                               float* __restrict__ sqn,
                                               unsigned* __restrict__ hpb,
                                               unsigned* __restrict__ hnb) {
    int t = blockIdx.x * 256 + threadIdx.x;
    int row = t >> 5;
    int kq = (t & 31) * 4;
    float4 v = *(const float4*)&E[(size_t)row * 128 + kq];
    float s = fmaf(v.x, v.x, fmaf(v.y, v.y, fmaf(v.z, v.z, v.w * v.w)));

    unsigned short hx = f2bf(v.x), hy = f2bf(v.y), hz = f2bf(v.z), hw = f2bf(v.w);
    unsigned short lx = f2bf(v.x - bf2f(hx)), ly = f2bf(v.y - bf2f(hy));
    unsigned short lz = f2bf(v.z - bf2f(hz)), lw = f2bf(v.w - bf2f(hw));
    ushort4 hi4; hi4.x = hx; hi4.y = hy; hi4.z = hz; hi4.w = hw;
    ushort4 lo4; lo4.x = lx; lo4.y = ly; lo4.z = lz; lo4.w = lw;
    *(ushort4*)&Ecat[(size_t)row * 256 + kq] = hi4;
    *(ushort4*)&Ecat[(size_t)row * 256 + 128 + kq] = lo4;

#pragma unroll
    for (int m = 1; m < 32; m <<= 1) s += __shfl_xor(s, m);
    if ((t & 31) == 0) {
        sqn[row] = s;
        hpb[row] = 0u;            // neutral for max(d2>=0)
        hnb[row] = 0x7F800000u;   // +inf
    }
}

// grid (32,16) x 256 threads. Block tile 128 x 256 (js-loop of 2 x 128).
// 4 waves in 2x2; wave tile 64x64 = 4x4 MFMA 16x16 tiles.
__global__ __launch_bounds__(256) void tl_phase1(const unsigned short* __restrict__ Ecat,
                                                 const int* __restrict__ labels,
                                                 const float* __restrict__ sqn,
                                                 unsigned* __restrict__ hpb,
                                                 unsigned* __restrict__ hnb) {
    __shared__ unsigned short Al[128 * WST];
    __shared__ unsigned short Bl[128 * WST];
    const int tid = threadIdx.x;
    const int l = tid & 63, w = tid >> 6;
    const int wr = w >> 1, wc = w & 1;
    const int q = l >> 4, r16 = l & 15;
    const int i0 = blockIdx.x * 128;
    const int jgrp = blockIdx.y * 256;

    float mp[4][4], mn[4][4];
    int li[4][4];
    float si[4][4];
#pragma unroll
    for (int ti = 0; ti < 4; ++ti)
#pragma unroll
        for (int p = 0; p < 4; ++p) {
            mp[ti][p] = 0.0f;
            mn[ti][p] = 3.4e38f;
            int rrow = i0 + wr * 64 + ti * 16 + q * 4 + p;
            li[ti][p] = labels[rrow];
            si[ti][p] = sqn[rrow];
        }

    for (int js = 0; js < 2; ++js) {
        const int jb = jgrp + js * 128;
        f32x4 acc[4][4];
#pragma unroll
        for (int ti = 0; ti < 4; ++ti)
#pragma unroll
            for (int tj = 0; tj < 4; ++tj) acc[ti][tj] = (f32x4)0.0f;

        for (int kc = 0; kc < 4; ++kc) {
            __syncthreads();  // protect previous-iter LDS reads
#pragma unroll
            for (int it = 0; it < 4; ++it) {
                int idx = it * 256 + tid;
                int rr = idx >> 3, ko = (idx & 7) * 8;
                *(short8*)&Al[rr * WST + ko] =
                    *(const short8*)&Ecat[(size_t)(i0 + rr) * 256 + kc * 64 + ko];
                *(short8*)&Bl[rr * WST + ko] =
                    *(const short8*)&Ecat[(size_t)(jb + rr) * 256 + kc * 64 + ko];
            }
            __syncthreads();
#pragma unroll
            for (int s = 0; s < 2; ++s) {
                short8 af[4], bf[4];
#pragma unroll
                for (int t2 = 0; t2 < 4; ++t2) {
                    af[t2] = *(const short8*)&Al[(wr * 64 + t2 * 16 + r16) * WST + s * 32 + q * 8];
                    bf[t2] = *(const short8*)&Bl[(wc * 64 + t2 * 16 + r16) * WST + s * 32 + q * 8];
                }
#pragma unroll
                for (int ti = 0; ti < 4; ++ti)
#pragma unroll
                    for (int tj = 0; tj < 4; ++tj)
                        acc[ti][tj] = __builtin_amdgcn_mfma_f32_16x16x32_bf16(
                            af[ti], bf[tj], acc[ti][tj], 0, 0, 0);
            }
        }
        // epilogue: d2 = si + sj - 2g, mine max-pos / min-neg on d2
#pragma unroll
        for (int tj = 0; tj < 4; ++tj) {
            int cj = jb + wc * 64 + tj * 16 + r16;
            int ljv = labels[cj];
            float sjv = sqn[cj];
#pragma unroll
            for (int ti = 0; ti < 4; ++ti) {
#pragma unroll
                for (int p = 0; p < 4; ++p) {
                    float g = acc[ti][tj][p];
                    float d2 = fmaf(-2.0f, g, si[ti][p] + sjv);
                    d2 = fmaxf(d2, 0.0f);
                    int rrow = i0 + wr * 64 + ti * 16 + q * 4 + p;
                    bool same = (li[ti][p] == ljv);
                    bool posok = same && (rrow != cj);
                    mp[ti][p] = fmaxf(mp[ti][p], posok ? d2 : 0.0f);
                    mn[ti][p] = fminf(mn[ti][p], same ? 3.4e38f : d2);
                }
            }
        }
    }
    // reduce across the 16 column-lanes of each quad (rows differ per quad)
#pragma unroll
    for (int ti = 0; ti < 4; ++ti)
#pragma unroll
        for (int p = 0; p < 4; ++p) {
            float a = mp[ti][p], b = mn[ti][p];
#pragma unroll
            for (int m = 1; m < 16; m <<= 1) {
                a = fmaxf(a, __shfl_xor(a, m));
                b = fminf(b, __shfl_xor(b, m));
            }
            if (r16 == 0) {
                int rrow = i0 + wr * 64 + ti * 16 + q * 4 + p;
                atomicMax(&hpb[rrow], __float_as_uint(a));   // d2 >= 0: uint order ok
                atomicMin(&hnb[rrow], __float_as_uint(b));
            }
        }
}

// single block, 1024 threads
__global__ __launch_bounds__(1024) void tl_phase2(const int* __restrict__ labels,
                                                  const unsigned* __restrict__ hpb,
                                                  const unsigned* __restrict__ hnb,
                                                  float* __restrict__ out) {
    __shared__ unsigned hist[256];
    __shared__ float sp[16], sv[16];
    int tid = threadIdx.x;
    if (tid < 256) hist[tid] = 0u;
    __syncthreads();
#pragma unroll
    for (int k = 0; k < 4; ++k) atomicAdd(&hist[labels[tid + k * 1024]], 1u);
    __syncthreads();
    float sum = 0.0f, nv = 0.0f;
#pragma unroll
    for (int k = 0; k < 4; ++k) {
        int r = tid + k * 1024;
        unsigned cnt = hist[labels[r]];
        bool valid = (cnt >= 2u) && (cnt < 4096u);
        float hp = sqrtf(__uint_as_float(hpb[r]));
        float hn = sqrtf(__uint_as_float(hnb[r]));
        float pr = fmaxf(hp - hn + MARGIN_F, 0.0f);
        if (valid) { sum += pr; nv += 1.0f; }
    }
#pragma unroll
    for (int m = 1; m < 64; m <<= 1) {
        sum += __shfl_xor(sum, m);
        nv += __shfl_xor(nv, m);
    }
    int wv = tid >> 6;
    if ((tid & 63) == 0) { sp[wv] = sum; sv[wv] = nv; }
    __syncthreads();
    if (tid == 0) {
        float ts = 0.0f, tn = 0.0f;
#pragma unroll
        for (int i = 0; i < 16; ++i) { ts += sp[i]; tn += sv[i]; }
        out[0] = ts / fmaxf(tn, 1.0f);
    }
}

extern "C" void kernel_launch(void* const* d_in, const int* in_sizes, int n_in,
                              void* d_out, int out_size, void* d_ws, size_t ws_size,
                              hipStream_t stream) {
    const float* E = (const float*)d_in[0];
    const int* labels = (const int*)d_in[1];
    float* out = (float*)d_out;

    // ws: Ecat 4096*256*2B = 2 MB | sqn 16 KB | hpb 16 KB | hnb 16 KB
    unsigned short* Ecat = (unsigned short*)d_ws;
    char* base = (char*)d_ws + (size_t)4096 * 256 * 2;
    float* sqn = (float*)base;
    unsigned* hpb = (unsigned*)(base + 16384);
    unsigned* hnb = (unsigned*)(base + 32768);

    tl_prep<<<512, 256, 0, stream>>>(E, Ecat, sqn, hpb, hnb);
    tl_phase1<<<dim3(32, 16), 256, 0, stream>>>(Ecat, labels, sqn, hpb, hnb);
    tl_phase2<<<1, 1024, 0, stream>>>(labels, hpb, hnb, out);
}

// Round 3
// 86.837 us; speedup vs baseline: 1.4983x; 1.0151x over previous
//
#include <hip/hip_runtime.h>
#include <hip/hip_bf16.h>

// TripletLoss B=4096 D=128 fp32. Batch-hard via bf16 hi/lo MFMA Gram.
// R3: exploit Gram symmetry — upper-triangular 128x128 block pairs only
// (528 blocks vs 1024-equiv). Off-diagonal blocks mine BOTH row-side
// (i-rows) and col-side (j-rows, quad-shuffle reduction over the C-layout
// row axis). Diagonal blocks stage one LDS tile and mine row-side only
// (their tile already contains both (r,c) and (c,r)).

typedef __attribute__((ext_vector_type(8))) short short8;
typedef __attribute__((ext_vector_type(4))) float f32x4;

#define MARGIN_F 0.3f
#define WST 72  // LDS row stride in bf16 (16B-aligned rows)

__device__ inline unsigned short f2bf(float x) {
    __hip_bfloat16 h = __float2bfloat16(x);
    return *(unsigned short*)&h;
}
__device__ inline float bf2f(unsigned short u) {
    __hip_bfloat16 h;
    *(unsigned short*)&h = u;
    return __bfloat162float(h);
}

// grid 512 x 256: 32 threads per row (4096 rows)
__global__ __launch_bounds__(256) void tl_prep(const float* __restrict__ E,
                                               unsigned short* __restrict__ Ecat,
                                               float* __restrict__ sqn,
                                               unsigned* __restrict__ hpb,
                                               unsigned* __restrict__ hnb) {
    int t = blockIdx.x * 256 + threadIdx.x;
    int row = t >> 5;
    int kq = (t & 31) * 4;
    float4 v = *(const float4*)&E[(size_t)row * 128 + kq];
    float s = fmaf(v.x, v.x, fmaf(v.y, v.y, fmaf(v.z, v.z, v.w * v.w)));

    unsigned short hx = f2bf(v.x), hy = f2bf(v.y), hz = f2bf(v.z), hw = f2bf(v.w);
    unsigned short lx = f2bf(v.x - bf2f(hx)), ly = f2bf(v.y - bf2f(hy));
    unsigned short lz = f2bf(v.z - bf2f(hz)), lw = f2bf(v.w - bf2f(hw));
    ushort4 hi4; hi4.x = hx; hi4.y = hy; hi4.z = hz; hi4.w = hw;
    ushort4 lo4; lo4.x = lx; lo4.y = ly; lo4.z = lz; lo4.w = lw;
    *(ushort4*)&Ecat[(size_t)row * 256 + kq] = hi4;
    *(ushort4*)&Ecat[(size_t)row * 256 + 128 + kq] = lo4;

#pragma unroll
    for (int m = 1; m < 32; m <<= 1) s += __shfl_xor(s, m);
    if ((t & 31) == 0) {
        sqn[row] = s;
        hpb[row] = 0u;            // neutral for max(d2>=0)
        hnb[row] = 0x7F800000u;   // +inf
    }
}

// grid 528 (upper-tri pairs of 32x32 128-tiles), 256 threads, 4 waves 2x2,
// wave tile 64x64 = 4x4 MFMA 16x16 tiles, K=256 in 4 chunks of 64.
__global__ __launch_bounds__(256) void tl_phase1(const unsigned short* __restrict__ Ecat,
                                                 const int* __restrict__ labels,
                                                 const float* __restrict__ sqn,
                                                 unsigned* __restrict__ hpb,
                                                 unsigned* __restrict__ hnb) {
    __shared__ unsigned short Al[128 * WST];
    __shared__ unsigned short Bl[128 * WST];

    // decode flat block id -> (bi, bj), bj >= bi;  off(b) = b*(65-b)/2
    const int t = blockIdx.x;
    int bi = (int)((65.0f - sqrtf(4225.0f - 8.0f * (float)t)) * 0.5f);
    bi = min(max(bi, 0), 31);
    while (bi < 31 && ((bi + 1) * (65 - (bi + 1))) / 2 <= t) ++bi;
    while (bi > 0 && (bi * (65 - bi)) / 2 > t) --bi;
    const int bj = bi + (t - (bi * (65 - bi)) / 2);
    const bool diag = (bi == bj);
    const int i0 = bi * 128, j0 = bj * 128;

    const int tid = threadIdx.x;
    const int l = tid & 63, w = tid >> 6;
    const int wr = w >> 1, wc = w & 1;
    const int q = l >> 4, r16 = l & 15;

    float mp[4][4], mn[4][4], si[4][4];
    int li[4][4];
#pragma unroll
    for (int ti = 0; ti < 4; ++ti)
#pragma unroll
        for (int p = 0; p < 4; ++p) {
            mp[ti][p] = 0.0f;
            mn[ti][p] = 3.4e38f;
            int rrow = i0 + wr * 64 + ti * 16 + q * 4 + p;
            li[ti][p] = labels[rrow];
            si[ti][p] = sqn[rrow];
        }

    f32x4 acc[4][4];
#pragma unroll
    for (int ti = 0; ti < 4; ++ti)
#pragma unroll
        for (int tj = 0; tj < 4; ++tj) acc[ti][tj] = (f32x4)0.0f;

    const unsigned short* Bsel = diag ? Al : Bl;

    for (int kc = 0; kc < 4; ++kc) {
        __syncthreads();  // protect previous-iter LDS reads
#pragma unroll
        for (int it = 0; it < 4; ++it) {
            int idx = it * 256 + tid;
            int rr = idx >> 3, ko = (idx & 7) * 8;
            *(short8*)&Al[rr * WST + ko] =
                *(const short8*)&Ecat[(size_t)(i0 + rr) * 256 + kc * 64 + ko];
            if (!diag)
                *(short8*)&Bl[rr * WST + ko] =
                    *(const short8*)&Ecat[(size_t)(j0 + rr) * 256 + kc * 64 + ko];
        }
        __syncthreads();
#pragma unroll
        for (int s = 0; s < 2; ++s) {
            short8 af[4], bf[4];
#pragma unroll
            for (int t2 = 0; t2 < 4; ++t2) {
                af[t2] = *(const short8*)&Al[(wr * 64 + t2 * 16 + r16) * WST + s * 32 + q * 8];
                bf[t2] = *(const short8*)&Bsel[(wc * 64 + t2 * 16 + r16) * WST + s * 32 + q * 8];
            }
#pragma unroll
            for (int ti = 0; ti < 4; ++ti)
#pragma unroll
                for (int tj = 0; tj < 4; ++tj)
                    acc[ti][tj] = __builtin_amdgcn_mfma_f32_16x16x32_bf16(
                        af[ti], bf[tj], acc[ti][tj], 0, 0, 0);
        }
    }

    // epilogue: d2 = si + sj - 2g; row-side mining always, col-side if off-diag
#pragma unroll
    for (int tj = 0; tj < 4; ++tj) {
        int cj = j0 + wc * 64 + tj * 16 + r16;
        int ljv = labels[cj];
        float sjv = sqn[cj];
        float cMP = 0.0f, cMN = 3.4e38f;
#pragma unroll
        for (int ti = 0; ti < 4; ++ti) {
#pragma unroll
            for (int p = 0; p < 4; ++p) {
                float g = acc[ti][tj][p];
                float d2 = fmaxf(fmaf(-2.0f, g, si[ti][p] + sjv), 0.0f);
                bool same = (li[ti][p] == ljv);
                int rrow = i0 + wr * 64 + ti * 16 + q * 4 + p;
                bool self = diag && (rrow == cj);
                mp[ti][p] = fmaxf(mp[ti][p], (same && !self) ? d2 : 0.0f);
                mn[ti][p] = fminf(mn[ti][p], same ? 3.4e38f : d2);
                cMP = fmaxf(cMP, same ? d2 : 0.0f);
                cMN = fminf(cMN, same ? 3.4e38f : d2);
            }
        }
        if (!diag) {
            cMP = fmaxf(cMP, __shfl_xor(cMP, 16));
            cMP = fmaxf(cMP, __shfl_xor(cMP, 32));
            cMN = fminf(cMN, __shfl_xor(cMN, 16));
            cMN = fminf(cMN, __shfl_xor(cMN, 32));
            if (l < 16) {
                atomicMax(&hpb[cj], __float_as_uint(cMP));
                atomicMin(&hnb[cj], __float_as_uint(cMN));
            }
        }
    }
    // row-side: reduce across the 16 column-lanes of each quad
#pragma unroll
    for (int ti = 0; ti < 4; ++ti)
#pragma unroll
        for (int p = 0; p < 4; ++p) {
            float a = mp[ti][p], b = mn[ti][p];
#pragma unroll
            for (int m = 1; m < 16; m <<= 1) {
                a = fmaxf(a, __shfl_xor(a, m));
                b = fminf(b, __shfl_xor(b, m));
            }
            if (r16 == 0) {
                int rrow = i0 + wr * 64 + ti * 16 + q * 4 + p;
                atomicMax(&hpb[rrow], __float_as_uint(a));
                atomicMin(&hnb[rrow], __float_as_uint(b));
            }
        }
}

// single block, 1024 threads
__global__ __launch_bounds__(1024) void tl_phase2(const int* __restrict__ labels,
                                                  const unsigned* __restrict__ hpb,
                                                  const unsigned* __restrict__ hnb,
                                                  float* __restrict__ out) {
    __shared__ unsigned hist[256];
    __shared__ float sp[16], sv[16];
    int tid = threadIdx.x;
    if (tid < 256) hist[tid] = 0u;
    __syncthreads();
#pragma unroll
    for (int k = 0; k < 4; ++k) atomicAdd(&hist[labels[tid + k * 1024]], 1u);
    __syncthreads();
    float sum = 0.0f, nv = 0.0f;
#pragma unroll
    for (int k = 0; k < 4; ++k) {
        int r = tid + k * 1024;
        unsigned cnt = hist[labels[r]];
        bool valid = (cnt >= 2u) && (cnt < 4096u);
        float hp = sqrtf(__uint_as_float(hpb[r]));
        float hn = sqrtf(__uint_as_float(hnb[r]));
        float pr = fmaxf(hp - hn + MARGIN_F, 0.0f);
        if (valid) { sum += pr; nv += 1.0f; }
    }
#pragma unroll
    for (int m = 1; m < 64; m <<= 1) {
        sum += __shfl_xor(sum, m);
        nv += __shfl_xor(nv, m);
    }
    int wv = tid >> 6;
    if ((tid & 63) == 0) { sp[wv] = sum; sv[wv] = nv; }
    __syncthreads();
    if (tid == 0) {
        float ts = 0.0f, tn = 0.0f;
#pragma unroll
        for (int i = 0; i < 16; ++i) { ts += sp[i]; tn += sv[i]; }
        out[0] = ts / fmaxf(tn, 1.0f);
    }
}

extern "C" void kernel_launch(void* const* d_in, const int* in_sizes, int n_in,
                              void* d_out, int out_size, void* d_ws, size_t ws_size,
                              hipStream_t stream) {
    const float* E = (const float*)d_in[0];
    const int* labels = (const int*)d_in[1];
    float* out = (float*)d_out;

    // ws: Ecat 4096*256*2B = 2 MB | sqn 16 KB | hpb 16 KB | hnb 16 KB
    unsigned short* Ecat = (unsigned short*)d_ws;
    char* base = (char*)d_ws + (size_t)4096 * 256 * 2;
    float* sqn = (float*)base;
    unsigned* hpb = (unsigned*)(base + 16384);
    unsigned* hnb = (unsigned*)(base + 32768);

    tl_prep<<<512, 256, 0, stream>>>(E, Ecat, sqn, hpb, hnb);
    tl_phase1<<<528, 256, 0, stream>>>(Ecat, labels, sqn, hpb, hnb);
    tl_phase2<<<1, 1024, 0, stream>>>(labels, hpb, hnb, out);
}

// Round 4
// 82.166 us; speedup vs baseline: 1.5835x; 1.0569x over previous
//
#include <hip/hip_runtime.h>
#include <hip/hip_bf16.h>

// TripletLoss B=4096 D=128 fp32. bf16 hi/lo split MFMA Gram (K=256).
// R4: atomic-free mining. phase1 grid (32,32), one 128x128 tile/block,
// global_load_lds(16B) staging into XOR-swizzled LDS (conflict-free
// ds_read_b128 frags), mine max/min of (sq[j] - 2*gram) per row into
// per-(jblock,row) partial buffers (coalesced stores, no atomics).
// phase2 folds 32 partials/row, adds sq[i], sqrt, validity via per-block
// label histogram, ticket-counter finalize (no 4th launch).

typedef __attribute__((ext_vector_type(8))) short short8;
typedef __attribute__((ext_vector_type(4))) float f32x4;

#define MARGIN_F 0.3f
#define NEG_BIG -3.4e38f
#define POS_BIG 3.4e38f

__device__ __forceinline__ void gl_lds16(const void* g, void* l) {
    __builtin_amdgcn_global_load_lds(
        (const __attribute__((address_space(1))) void*)g,
        (__attribute__((address_space(3))) void*)l, 16, 0, 0);
}

__device__ inline unsigned short f2bf(float x) {
    union { __hip_bfloat16 h; unsigned short u; } c;
    c.h = __float2bfloat16(x);
    return c.u;
}
__device__ inline float bf2f(unsigned short u) {
    union { __hip_bfloat16 h; unsigned short us; } c;
    c.us = u;
    return __bfloat162float(c.h);
}

// grid 512 x 256: 32 threads per row. Convert E -> [hi|lo] bf16, sqn, zero accum.
__global__ __launch_bounds__(256) void tl_prep(const float* __restrict__ E,
                                               unsigned short* __restrict__ Ecat,
                                               float* __restrict__ sqn,
                                               unsigned* __restrict__ accum) {
    int t = blockIdx.x * 256 + threadIdx.x;
    if (t < 4) accum[t] = 0u;
    int row = t >> 5;
    int kq = (t & 31) * 4;
    float4 v = *(const float4*)&E[(size_t)row * 128 + kq];
    float s = fmaf(v.x, v.x, fmaf(v.y, v.y, fmaf(v.z, v.z, v.w * v.w)));

    unsigned short hx = f2bf(v.x), hy = f2bf(v.y), hz = f2bf(v.z), hw = f2bf(v.w);
    unsigned short lx = f2bf(v.x - bf2f(hx)), ly = f2bf(v.y - bf2f(hy));
    unsigned short lz = f2bf(v.z - bf2f(hz)), lw = f2bf(v.w - bf2f(hw));
    ushort4 hi4; hi4.x = hx; hi4.y = hy; hi4.z = hz; hi4.w = hw;
    ushort4 lo4; lo4.x = lx; lo4.y = ly; lo4.z = lz; lo4.w = lw;
    *(ushort4*)&Ecat[(size_t)row * 256 + kq] = hi4;
    *(ushort4*)&Ecat[(size_t)row * 256 + 128 + kq] = lo4;

#pragma unroll
    for (int m = 1; m < 32; m <<= 1) s += __shfl_xor(s, m);
    if ((t & 31) == 0) sqn[row] = s;
}

// grid (32,32) x 256. 4 waves 2x2, wave tile 64x64 = 4x4 MFMA 16x16x32.
// LDS: unpadded 128x64 bf16 per buffer, chunk c of row r stored at column
// (c ^ (r&7)) -> global_load_lds lane-contiguous AND conflict-free b128 reads.
__global__ __launch_bounds__(256, 3) void tl_phase1(const unsigned short* __restrict__ Ecat,
                                                    const int* __restrict__ labels,
                                                    const float* __restrict__ sqn,
                                                    float* __restrict__ pmp,
                                                    float* __restrict__ pmn) {
    __shared__ __align__(16) unsigned short Al[128 * 64];
    __shared__ __align__(16) unsigned short Bl[128 * 64];
    __shared__ float mpS[2][128], mnS[2][128];

    const int tid = threadIdx.x;
    const int l = tid & 63, w = tid >> 6;
    const int wr = w >> 1, wc = w & 1;
    const int q = l >> 4, r16 = l & 15;
    const int i0 = blockIdx.x * 128, j0 = blockIdx.y * 128;

    // staging sources: slot s = w*256 + t2*64 + l; row=s>>3; src chunk = (s&7)^(row&7)
    const unsigned short* gA[4];
    const unsigned short* gB[4];
#pragma unroll
    for (int t2 = 0; t2 < 4; ++t2) {
        int s = w * 256 + t2 * 64 + l;
        int row = s >> 3, ch = (s & 7) ^ (row & 7);
        gA[t2] = Ecat + (size_t)(i0 + row) * 256 + ch * 8;
        gB[t2] = Ecat + (size_t)(j0 + row) * 256 + ch * 8;
    }

    f32x4 acc[4][4];
#pragma unroll
    for (int ti = 0; ti < 4; ++ti)
#pragma unroll
        for (int tj = 0; tj < 4; ++tj) acc[ti][tj] = (f32x4)0.0f;

    for (int kc = 0; kc < 4; ++kc) {
        __syncthreads();
#pragma unroll
        for (int t2 = 0; t2 < 4; ++t2) {
            gl_lds16(gA[t2] + kc * 64, &Al[w * 2048 + t2 * 512]);
            gl_lds16(gB[t2] + kc * 64, &Bl[w * 2048 + t2 * 512]);
        }
        __syncthreads();  // compiler drains vmcnt before barrier
#pragma unroll
        for (int s = 0; s < 2; ++s) {
            short8 af[4], bf[4];
            const int cA = ((s * 4 + q) ^ (r16 & 7)) * 8;
#pragma unroll
            for (int t2 = 0; t2 < 4; ++t2) {
                af[t2] = *(const short8*)&Al[(wr * 64 + t2 * 16 + r16) * 64 + cA];
                bf[t2] = *(const short8*)&Bl[(wc * 64 + t2 * 16 + r16) * 64 + cA];
            }
#pragma unroll
            for (int ti = 0; ti < 4; ++ti)
#pragma unroll
                for (int tj = 0; tj < 4; ++tj)
                    acc[ti][tj] = __builtin_amdgcn_mfma_f32_16x16x32_bf16(
                        af[ti], bf[tj], acc[ti][tj], 0, 0, 0);
        }
    }

    // epilogue: mine val = sq[j] - 2*g  (monotone in d2 for fixed row i)
    float mp[4][4], mn[4][4];
    int li[4][4];
#pragma unroll
    for (int ti = 0; ti < 4; ++ti)
#pragma unroll
        for (int p = 0; p < 4; ++p) {
            mp[ti][p] = NEG_BIG;
            mn[ti][p] = POS_BIG;
            li[ti][p] = labels[i0 + wr * 64 + ti * 16 + q * 4 + p];
        }
    const bool diagblk = (blockIdx.x == blockIdx.y);
#pragma unroll
    for (int tj = 0; tj < 4; ++tj) {
        int cj = j0 + wc * 64 + tj * 16 + r16;
        int ljv = labels[cj];
        float sjv = sqn[cj];
#pragma unroll
        for (int ti = 0; ti < 4; ++ti)
#pragma unroll
            for (int p = 0; p < 4; ++p) {
                float val = fmaf(-2.0f, acc[ti][tj][p], sjv);
                bool same = (li[ti][p] == ljv);
                bool self = diagblk && ((wr * 64 + ti * 16 + q * 4 + p) == (wc * 64 + tj * 16 + r16));
                mp[ti][p] = fmaxf(mp[ti][p], (same && !self) ? val : NEG_BIG);
                mn[ti][p] = fminf(mn[ti][p], same ? POS_BIG : val);
            }
    }
    // fold 16 column-lanes, stash per-wc into LDS, merge, coalesced store
#pragma unroll
    for (int ti = 0; ti < 4; ++ti)
#pragma unroll
        for (int p = 0; p < 4; ++p) {
            float a = mp[ti][p], b = mn[ti][p];
#pragma unroll
            for (int m = 1; m < 16; m <<= 1) {
                a = fmaxf(a, __shfl_xor(a, m));
                b = fminf(b, __shfl_xor(b, m));
            }
            if (r16 == 0) {
                int rloc = wr * 64 + ti * 16 + q * 4 + p;
                mpS[wc][rloc] = a;
                mnS[wc][rloc] = b;
            }
        }
    __syncthreads();
    if (tid < 128) {
        pmp[(size_t)blockIdx.y * 4096 + i0 + tid] = fmaxf(mpS[0][tid], mpS[1][tid]);
        pmn[(size_t)blockIdx.y * 4096 + i0 + tid] = fminf(mnS[0][tid], mnS[1][tid]);
    }
}

// grid 16 x 256: fold 32 partials/row, validity via full-batch LDS hist,
// block partial sums -> accum atomics, ticket-counter finalize.
__global__ __launch_bounds__(256) void tl_phase2(const int* __restrict__ labels,
                                                 const float* __restrict__ pmp,
                                                 const float* __restrict__ pmn,
                                                 const float* __restrict__ sqn,
                                                 float* __restrict__ accum,
                                                 float* __restrict__ out) {
    __shared__ unsigned hist[256];
    __shared__ float sp[4], sv[4];
    int tid = threadIdx.x;
    hist[tid] = 0u;
    __syncthreads();
#pragma unroll
    for (int k = 0; k < 16; ++k) atomicAdd(&hist[labels[k * 256 + tid]], 1u);
    __syncthreads();

    int r = blockIdx.x * 256 + tid;
    float mp = NEG_BIG, mn = POS_BIG;
#pragma unroll
    for (int k = 0; k < 32; ++k) {
        mp = fmaxf(mp, pmp[(size_t)k * 4096 + r]);
        mn = fminf(mn, pmn[(size_t)k * 4096 + r]);
    }
    float si = sqn[r];
    unsigned cnt = hist[labels[r]];
    bool valid = (cnt >= 2u) && (cnt < 4096u);
    float hp = sqrtf(fmaxf(si + mp, 0.0f));
    float hn = sqrtf(fmaxf(si + mn, 0.0f));
    float pr = fmaxf(hp - hn + MARGIN_F, 0.0f);
    float s = valid ? pr : 0.0f;
    float n = valid ? 1.0f : 0.0f;
#pragma unroll
    for (int m = 1; m < 64; m <<= 1) {
        s += __shfl_xor(s, m);
        n += __shfl_xor(n, m);
    }
    if ((tid & 63) == 0) { sp[tid >> 6] = s; sv[tid >> 6] = n; }
    __syncthreads();
    if (tid == 0) {
        float ts = sp[0] + sp[1] + sp[2] + sp[3];
        float tn = sv[0] + sv[1] + sv[2] + sv[3];
        atomicAdd(&accum[0], ts);
        atomicAdd(&accum[1], tn);
        __threadfence();
        unsigned tk = atomicAdd((unsigned*)&accum[2], 1u);
        if (tk == 15u) {
            float a = atomicAdd(&accum[0], 0.0f);  // coherent read
            float b = atomicAdd(&accum[1], 0.0f);
            out[0] = a / fmaxf(b, 1.0f);
        }
    }
}

extern "C" void kernel_launch(void* const* d_in, const int* in_sizes, int n_in,
                              void* d_out, int out_size, void* d_ws, size_t ws_size,
                              hipStream_t stream) {
    const float* E = (const float*)d_in[0];
    const int* labels = (const int*)d_in[1];
    float* out = (float*)d_out;

    // ws: Ecat 2 MB | pmp 512 KB | pmn 512 KB | sqn 16 KB | accum 16 B
    char* base = (char*)d_ws;
    unsigned short* Ecat = (unsigned short*)base;
    float* pmp = (float*)(base + (2u << 20));
    float* pmn = (float*)(base + (2u << 20) + (512u << 10));
    float* sqn = (float*)(base + (3u << 20));
    float* accum = (float*)(base + (3u << 20) + (16u << 10));

    tl_prep<<<512, 256, 0, stream>>>(E, Ecat, sqn, (unsigned*)accum);
    tl_phase1<<<dim3(32, 32), 256, 0, stream>>>(Ecat, labels, sqn, pmp, pmn);
    tl_phase2<<<16, 256, 0, stream>>>(labels, pmp, pmn, sqn, accum, out);
}

// Round 5
// 72.279 us; speedup vs baseline: 1.8001x; 1.1368x over previous
//
#include <hip/hip_runtime.h>
#include <hip/hip_bf16.h>

// TripletLoss B=4096 D=128 fp32. R5: pure-bf16 Gram K=128 (error ~= the
// validated [hi|lo] concat scheme, which only ever added lo*lo), single
// 128x128 tile/block grid (32,32), both K-chunks resident in LDS, raw
// s_barrier + fine vmcnt (no vmcnt(0) drain while prefetch in flight),
// LDS-fold epilogue (no shuffle storm), atomic-free partial stores.

typedef __attribute__((ext_vector_type(8))) short short8;
typedef __attribute__((ext_vector_type(4))) float f32x4;

#define MARGIN_F 0.3f
#define NEG_BIG -3.4e38f
#define POS_BIG 3.4e38f
// gfx9 waitcnt encoding: vmcnt[3:0]|[15:14], expcnt[6:4], lgkmcnt[11:8]
#define WAITVM(N) __builtin_amdgcn_s_waitcnt(((N)&15)|((((N)>>4)&3)<<14)|(7<<4)|(15<<8))

__device__ __forceinline__ void gl_lds16(const void* g, void* l) {
    __builtin_amdgcn_global_load_lds(
        (const __attribute__((address_space(1))) void*)g,
        (__attribute__((address_space(3))) void*)l, 16, 0, 0);
}

__device__ inline unsigned short f2bf(float x) {
    union { __hip_bfloat16 h; unsigned short u; } c;
    c.h = __float2bfloat16(x);
    return c.u;
}

// grid 512 x 256: 32 threads/row. bf16 convert + row norms + zero accum.
__global__ __launch_bounds__(256) void tl_prep(const float* __restrict__ E,
                                               unsigned short* __restrict__ Ebf,
                                               float* __restrict__ sqn,
                                               unsigned* __restrict__ accum) {
    int t = blockIdx.x * 256 + threadIdx.x;
    if (t < 4) accum[t] = 0u;
    int row = t >> 5;
    int kq = (t & 31) * 4;
    float4 v = *(const float4*)&E[(size_t)row * 128 + kq];
    float s = fmaf(v.x, v.x, fmaf(v.y, v.y, fmaf(v.z, v.z, v.w * v.w)));
    ushort4 h4;
    h4.x = f2bf(v.x); h4.y = f2bf(v.y); h4.z = f2bf(v.z); h4.w = f2bf(v.w);
    *(ushort4*)&Ebf[(size_t)row * 128 + kq] = h4;
#pragma unroll
    for (int m = 1; m < 32; m <<= 1) s += __shfl_xor(s, m);
    if ((t & 31) == 0) sqn[row] = s;
}

// grid (32,32) x 256. 4 waves 2x2, wave tile 64x64 = 4x4 MFMA 16x16x32.
// LDS per K-chunk: 128 rows x 64 bf16, chunk c of row r at column c^(r&7).
__global__ __launch_bounds__(256, 2) void tl_phase1(const unsigned short* __restrict__ Ebf,
                                                    const int* __restrict__ labels,
                                                    const float* __restrict__ sqn,
                                                    float* __restrict__ pmp,
                                                    float* __restrict__ pmn) {
    union SM {
        struct { unsigned short A[2][128 * 64]; unsigned short B[2][128 * 64]; } s;
        struct { float mp[128][32]; float mn[128][32]; } f;
    };
    __shared__ __align__(16) SM sm;

    const int tid = threadIdx.x;
    const int l = tid & 63, w = tid >> 6;
    const int wr = w >> 1, wc = w & 1;
    const int q = l >> 4, r16 = l & 15;
    const int i0 = blockIdx.x * 128, j0 = blockIdx.y * 128;

    // staging sources: slot s = w*256 + t2*64 + l; row=s>>3; chunk=(s&7)^(row&7)
    const unsigned short* gA[4];
    const unsigned short* gB[4];
#pragma unroll
    for (int t2 = 0; t2 < 4; ++t2) {
        int s = w * 256 + t2 * 64 + l;
        int row = s >> 3, ch = (s & 7) ^ (row & 7);
        gA[t2] = Ebf + (size_t)(i0 + row) * 128 + ch * 8;
        gB[t2] = Ebf + (size_t)(j0 + row) * 128 + ch * 8;
    }

    // prefetch epilogue metadata early (independent of staging)
    int li[4][4], lj[4];
    float sj[4];
#pragma unroll
    for (int ti = 0; ti < 4; ++ti)
#pragma unroll
        for (int p = 0; p < 4; ++p)
            li[ti][p] = labels[i0 + wr * 64 + ti * 16 + q * 4 + p];
#pragma unroll
    for (int tj = 0; tj < 4; ++tj) {
        int cj = j0 + wc * 64 + tj * 16 + r16;
        lj[tj] = labels[cj];
        sj[tj] = sqn[cj];
    }

    // issue all staging: chunk0 (8 loads) then chunk1 (8 loads)
#pragma unroll
    for (int t2 = 0; t2 < 4; ++t2) {
        gl_lds16(gA[t2], &sm.s.A[0][w * 2048 + t2 * 512]);
        gl_lds16(gB[t2], &sm.s.B[0][w * 2048 + t2 * 512]);
    }
#pragma unroll
    for (int t2 = 0; t2 < 4; ++t2) {
        gl_lds16(gA[t2] + 64, &sm.s.A[1][w * 2048 + t2 * 512]);
        gl_lds16(gB[t2] + 64, &sm.s.B[1][w * 2048 + t2 * 512]);
    }

    f32x4 acc[4][4];
#pragma unroll
    for (int ti = 0; ti < 4; ++ti)
#pragma unroll
        for (int tj = 0; tj < 4; ++tj) acc[ti][tj] = (f32x4)0.0f;

#pragma unroll
    for (int kc = 0; kc < 2; ++kc) {
        if (kc == 0) WAITVM(8); else WAITVM(0);
        __builtin_amdgcn_s_barrier();
#pragma unroll
        for (int s = 0; s < 2; ++s) {
            short8 af[4], bf[4];
            const int cA = ((s * 4 + q) ^ (r16 & 7)) * 8;
#pragma unroll
            for (int t2 = 0; t2 < 4; ++t2) {
                af[t2] = *(const short8*)&sm.s.A[kc][(wr * 64 + t2 * 16 + r16) * 64 + cA];
                bf[t2] = *(const short8*)&sm.s.B[kc][(wc * 64 + t2 * 16 + r16) * 64 + cA];
            }
#pragma unroll
            for (int ti = 0; ti < 4; ++ti)
#pragma unroll
                for (int tj = 0; tj < 4; ++tj)
                    acc[ti][tj] = __builtin_amdgcn_mfma_f32_16x16x32_bf16(
                        af[ti], bf[tj], acc[ti][tj], 0, 0, 0);
        }
    }

    // mine val = sq[j] - 2*g (monotone in d2 for fixed i) into registers
    float mp[4][4], mn[4][4];
#pragma unroll
    for (int ti = 0; ti < 4; ++ti)
#pragma unroll
        for (int p = 0; p < 4; ++p) { mp[ti][p] = NEG_BIG; mn[ti][p] = POS_BIG; }
    const bool diagblk = (blockIdx.x == blockIdx.y);
#pragma unroll
    for (int tj = 0; tj < 4; ++tj) {
#pragma unroll
        for (int ti = 0; ti < 4; ++ti)
#pragma unroll
            for (int p = 0; p < 4; ++p) {
                float val = fmaf(-2.0f, acc[ti][tj][p], sj[tj]);
                bool same = (li[ti][p] == lj[tj]);
                bool self = diagblk &&
                    ((wr * 64 + ti * 16 + q * 4 + p) == (wc * 64 + tj * 16 + r16));
                mp[ti][p] = fmaxf(mp[ti][p], (same && !self) ? val : NEG_BIG);
                mn[ti][p] = fminf(mn[ti][p], same ? POS_BIG : val);
            }
    }

    // LDS fold: 32 partials per row (16 col-lanes x 2 wc waves)
    __syncthreads();  // all LDS frag reads done before aliasing overwrite
#pragma unroll
    for (int ti = 0; ti < 4; ++ti)
#pragma unroll
        for (int p = 0; p < 4; ++p) {
            int rloc = wr * 64 + ti * 16 + q * 4 + p;
            sm.f.mp[rloc][wc * 16 + r16] = mp[ti][p];
            sm.f.mn[rloc][wc * 16 + r16] = mn[ti][p];
        }
    __syncthreads();
    {
        int row = tid >> 1, hf = tid & 1;
        const float4* P = (const float4*)&sm.f.mp[row][hf * 16];
        const float4* N = (const float4*)&sm.f.mn[row][hf * 16];
        float4 p0 = P[0], p1 = P[1], p2 = P[2], p3 = P[3];
        float4 n0 = N[0], n1 = N[1], n2 = N[2], n3 = N[3];
        float M = fmaxf(fmaxf(fmaxf(p0.x, p0.y), fmaxf(p0.z, p0.w)),
                        fmaxf(fmaxf(p1.x, p1.y), fmaxf(p1.z, p1.w)));
        M = fmaxf(M, fmaxf(fmaxf(fmaxf(p2.x, p2.y), fmaxf(p2.z, p2.w)),
                           fmaxf(fmaxf(p3.x, p3.y), fmaxf(p3.z, p3.w))));
        float m_ = fminf(fminf(fminf(n0.x, n0.y), fminf(n0.z, n0.w)),
                         fminf(fminf(n1.x, n1.y), fminf(n1.z, n1.w)));
        m_ = fminf(m_, fminf(fminf(fminf(n2.x, n2.y), fminf(n2.z, n2.w)),
                             fminf(fminf(n3.x, n3.y), fminf(n3.z, n3.w))));
        M = fmaxf(M, __shfl_xor(M, 1));
        m_ = fminf(m_, __shfl_xor(m_, 1));
        if (hf == 0) {
            pmp[(size_t)blockIdx.y * 4096 + i0 + row] = M;
            pmn[(size_t)blockIdx.y * 4096 + i0 + row] = m_;
        }
    }
}

// grid 16 x 256: fold 32 partials/row, validity via LDS label hist,
// ticket-counter finalize.
__global__ __launch_bounds__(256) void tl_phase2(const int* __restrict__ labels,
                                                 const float* __restrict__ pmp,
                                                 const float* __restrict__ pmn,
                                                 const float* __restrict__ sqn,
                                                 float* __restrict__ accum,
                                                 float* __restrict__ out) {
    __shared__ unsigned hist[256];
    __shared__ float sp[4], sv[4];
    int tid = threadIdx.x;
    hist[tid] = 0u;
    __syncthreads();
#pragma unroll
    for (int k = 0; k < 16; ++k) atomicAdd(&hist[labels[k * 256 + tid]], 1u);
    __syncthreads();

    int r = blockIdx.x * 256 + tid;
    float mp = NEG_BIG, mn = POS_BIG;
#pragma unroll
    for (int k = 0; k < 32; ++k) {
        mp = fmaxf(mp, pmp[(size_t)k * 4096 + r]);
        mn = fminf(mn, pmn[(size_t)k * 4096 + r]);
    }
    float si = sqn[r];
    unsigned cnt = hist[labels[r]];
    bool valid = (cnt >= 2u) && (cnt < 4096u);
    float hp = sqrtf(fmaxf(si + mp, 0.0f));
    float hn = sqrtf(fmaxf(si + mn, 0.0f));
    float pr = fmaxf(hp - hn + MARGIN_F, 0.0f);
    float s = valid ? pr : 0.0f;
    float n = valid ? 1.0f : 0.0f;
#pragma unroll
    for (int m = 1; m < 64; m <<= 1) {
        s += __shfl_xor(s, m);
        n += __shfl_xor(n, m);
    }
    if ((tid & 63) == 0) { sp[tid >> 6] = s; sv[tid >> 6] = n; }
    __syncthreads();
    if (tid == 0) {
        float ts = sp[0] + sp[1] + sp[2] + sp[3];
        float tn = sv[0] + sv[1] + sv[2] + sv[3];
        atomicAdd(&accum[0], ts);
        atomicAdd(&accum[1], tn);
        __threadfence();
        unsigned tk = atomicAdd((unsigned*)&accum[2], 1u);
        if (tk == 15u) {
            float a = atomicAdd(&accum[0], 0.0f);
            float b = atomicAdd(&accum[1], 0.0f);
            out[0] = a / fmaxf(b, 1.0f);
        }
    }
}

extern "C" void kernel_launch(void* const* d_in, const int* in_sizes, int n_in,
                              void* d_out, int out_size, void* d_ws, size_t ws_size,
                              hipStream_t stream) {
    const float* E = (const float*)d_in[0];
    const int* labels = (const int*)d_in[1];
    float* out = (float*)d_out;

    // ws: Ebf 1 MB | pmp 512 KB | pmn 512 KB | sqn 16 KB | accum
    char* base = (char*)d_ws;
    unsigned short* Ebf = (unsigned short*)base;
    float* pmp = (float*)(base + (1u << 20));
    float* pmn = (float*)(base + (1u << 20) + (512u << 10));
    float* sqn = (float*)(base + (2u << 20));
    float* accum = (float*)(base + (2u << 20) + (16u << 10));

    tl_prep<<<512, 256, 0, stream>>>(E, Ebf, sqn, (unsigned*)accum);
    tl_phase1<<<dim3(32, 32), 256, 0, stream>>>(Ebf, labels, sqn, pmp, pmn);
    tl_phase2<<<16, 256, 0, stream>>>(labels, pmp, pmn, sqn, accum, out);
}